// Round 8
// baseline (125.481 us; speedup 1.0000x reference)
//
#include <hip/hip_runtime.h>
#include <hip/hip_bf16.h>

// Problem constants (B, NBC, H, W, HID, OUT = 4, 128, 64, 64, 64, 1)
// ALL tensors are float32 (reference uses jnp.float32 throughout).
#define BB   4
#define NBC  128
#define NINT 4096
#define HID  64

using short8  = __attribute__((ext_vector_type(8)))  short;  // 8 bf16 (4 VGPRs)
using float16 = __attribute__((ext_vector_type(16))) float;  // MFMA 32x32 acc
using f2      = __attribute__((ext_vector_type(2)))  float;
using int4v   = __attribute__((ext_vector_type(4)))  int;

static __device__ __forceinline__ short f2bf(float f) {  // RNE, weights only
    __hip_bfloat16 h = __float2bfloat16(f);
    return __builtin_bit_cast(short, h);
}
static __device__ __forceinline__ unsigned fbits(float f) {
    return __builtin_bit_cast(unsigned, f);
}
// pack trunc-bf16(lo), trunc-bf16(hi) into one dword (verified R2-R7)
static __device__ __forceinline__ unsigned pack_bf_trunc(float lo, float hi) {
    return __builtin_amdgcn_perm(fbits(hi), fbits(lo), 0x07060302u);
}

// ---------------------------------------------------------------------------
// Kernel 1: boundary encoder + a' -> ws; ALSO zero-inits out (for atomics).
// ---------------------------------------------------------------------------
__global__ void __launch_bounds__(256) bge_prep(
    const float* __restrict__ binfo,  // (4,128,3)
    const float* __restrict__ W0,     // (3,64)
    const float* __restrict__ b0,     // (64)
    const float* __restrict__ W1,     // (64,64)
    const float* __restrict__ b1,     // (64)
    const float* __restrict__ G0w,    // (66,64)
    const float* __restrict__ G0b,    // (64)
    float* __restrict__ aprime,       // (4,128,64)
    float* __restrict__ out)          // (4,4096) -> zeroed here
{
    __shared__ float sW1[HID * HID];
    __shared__ float sG0[HID * HID];
    __shared__ float shv [4][HID];
    __shared__ float shv2[4][HID];

    const int tid = threadIdx.x;
    const int wv  = tid >> 6;
    const int t   = tid & 63;
    const int row = blockIdx.x * 4 + wv;

    // zero the output (harness poisons it 0xAA before every launch)
    const int g = blockIdx.x * 256 + tid;
    if (g < BB * NINT) out[g] = 0.0f;

    for (int idx = tid; idx < HID * HID / 4; idx += 256) {
        ((float4*)sW1)[idx] = ((const float4*)W1)[idx];
        ((float4*)sG0)[idx] = ((const float4*)G0w)[idx];
    }

    const float x0 = binfo[row*3+0];
    const float x1 = binfo[row*3+1];
    const float x2 = binfo[row*3+2];
    float h = fmaxf(x0*W0[t] + x1*W0[64+t] + x2*W0[128+t] + b0[t], 0.0f);
    shv[wv][t] = h;
    __syncthreads();

    float acc = b1[t];
    #pragma unroll 8
    for (int k = 0; k < HID; ++k) acc += shv[wv][k] * sW1[k*64 + t];
    shv2[wv][t] = fmaxf(acc, 0.0f);
    __syncthreads();

    float a = G0b[t];
    #pragma unroll 8
    for (int k = 0; k < HID; ++k) a += shv2[wv][k] * sG0[k*64 + t];
    aprime[row*HID + t] = a;
}

// ---------------------------------------------------------------------------
// Kernel 2 (R8): R5 structure (best so far) + bc z-split for TLP + bias trick.
// grid (128, 4, 2): i-tile of 32, batch, bc-half. 512 thr = 8 waves;
// wave wv handles bc [zh*64 + wv*8, +8).
// MFMA 32x32x16 bf16 [verified R2-R7]:
//   A[m=lane&31][k=hf*8+jj(+16st)], B[k][n=lane&31],
//   C/D: col=lane&31, row=(reg&3)+8*(reg>>2)+4*hf.
// Epilogue bias trick: relu(x+b) = max(x,-b)+b -> max vs -b1 only; exact
// correction 8*(b1.g2) added once per wave. Halves merged via atomicAdd.
// NOTE: no second __launch_bounds__ arg (R4: it forces spills).
// ---------------------------------------------------------------------------
__global__ void __launch_bounds__(512) bge_main(
    const float* __restrict__ icoord, // (4,4096,2)
    const float* __restrict__ G0w,    // (66,64)  rows 64,65 used here
    const float* __restrict__ G1w,    // (64,64)
    const float* __restrict__ G1b,    // (64)
    const float* __restrict__ G2w,    // (64,1)
    const float* __restrict__ G2b,    // (1)
    const float* __restrict__ aprime, // (4,128,64) fp32
    float* __restrict__ out)          // (4,4096), pre-zeroed
{
    // union: ldsA (4096 floats, this bc-half) reused as ldsS (8704) + red (512)
    __shared__ __align__(16) float smem[8704 + 512];   // 36 KB
    float* const ldsA = smem;
    float* const ldsS = smem;
    float* const red  = smem + 8704;

    const int b    = blockIdx.y;
    const int i0   = blockIdx.x * 32;
    const int zh   = blockIdx.z;     // bc half (0/1)
    const int tid  = threadIdx.x;
    const int wv   = tid >> 6;       // 0..7
    const int lane = tid & 63;
    const int hf   = lane >> 5;
    const int ln   = lane & 31;

    // stage this half's 64 a' rows into LDS (16 KB), coalesced float4
    {
        const float4* src = (const float4*)(aprime + ((size_t)b*NBC + zh*64) * HID);
        float4* dst = (float4*)ldsA;
        #pragma unroll
        for (int idx = tid; idx < 64*HID/4; idx += 512) dst[idx] = src[idx];
    }

    // per-lane c contribution: cre4[st][h] for k = st*16 + hf*8 + h*4 .. +3
    const float2 cc = ((const float2*)icoord)[(size_t)b*NINT + i0 + ln];
    float4 cre4[4][2];
    #pragma unroll
    for (int st = 0; st < 4; ++st)
        #pragma unroll
        for (int h = 0; h < 2; ++h) {
            const int k = st*16 + hf*8 + h*4;
            cre4[st][h] = make_float4(
                cc.x*G0w[64*64 + k+0] + cc.y*G0w[65*64 + k+0],
                cc.x*G0w[64*64 + k+1] + cc.y*G0w[65*64 + k+1],
                cc.x*G0w[64*64 + k+2] + cc.y*G0w[65*64 + k+2],
                cc.x*G0w[64*64 + k+3] + cc.y*G0w[65*64 + k+3]);
        }

    // B fragments of G1w (fp32 -> bf16 RNE, once): k = st*16+hf*8+jj, n = t*32+ln
    short8 bfrag[4][2];
    #pragma unroll
    for (int st = 0; st < 4; ++st)
        #pragma unroll
        for (int t = 0; t < 2; ++t)
            #pragma unroll
            for (int jj = 0; jj < 8; ++jj) {
                const int k = st*16 + hf*8 + jj;
                bfrag[st][t][jj] = f2bf(G1w[k*64 + t*32 + ln]);
            }

    const float b1v0 = G1b[ln],  b1v1 = G1b[32 + ln];
    const float g2v0 = G2w[ln],  g2v1 = G2w[32 + ln];
    const float nb0 = -b1v0, nb1 = -b1v1;

    const float16 zc = (float16)0.0f;
    f2 s2[8];
    #pragma unroll
    for (int q = 0; q < 8; ++q) s2[q] = (f2)0.0f;

    __syncthreads();  // ldsA ready

    const float* arow = ldsA + (wv*8)*HID;
    #pragma unroll 2
    for (int it = 0; it < 8; ++it, arow += HID) {
        float16 acc0, acc1;
        #pragma unroll
        for (int st = 0; st < 4; ++st) {
            const float4* ap4 = (const float4*)(arow + st*16 + hf*8); // bcast/half
            float4 v0 = ap4[0], v1 = ap4[1];
            const float4 c0 = cre4[st][0], c1 = cre4[st][1];
            v0.x = fmaxf(v0.x + c0.x, 0.0f); v0.y = fmaxf(v0.y + c0.y, 0.0f);
            v0.z = fmaxf(v0.z + c0.z, 0.0f); v0.w = fmaxf(v0.w + c0.w, 0.0f);
            v1.x = fmaxf(v1.x + c1.x, 0.0f); v1.y = fmaxf(v1.y + c1.y, 0.0f);
            v1.z = fmaxf(v1.z + c1.z, 0.0f); v1.w = fmaxf(v1.w + c1.w, 0.0f);
            int4v di;
            di[0] = (int)pack_bf_trunc(v0.x, v0.y);
            di[1] = (int)pack_bf_trunc(v0.z, v0.w);
            di[2] = (int)pack_bf_trunc(v1.x, v1.y);
            di[3] = (int)pack_bf_trunc(v1.z, v1.w);
            const short8 af = __builtin_bit_cast(short8, di);
            if (st == 0) {
                acc0 = __builtin_amdgcn_mfma_f32_32x32x16_bf16(af, bfrag[0][0], zc, 0, 0, 0);
                acc1 = __builtin_amdgcn_mfma_f32_32x32x16_bf16(af, bfrag[0][1], zc, 0, 0, 0);
            } else {
                acc0 = __builtin_amdgcn_mfma_f32_32x32x16_bf16(af, bfrag[st][0], acc0, 0, 0, 0);
                acc1 = __builtin_amdgcn_mfma_f32_32x32x16_bf16(af, bfrag[st][1], acc1, 0, 0, 0);
            }
        }
        // epilogue: s += max(h2,-b1)*g2  (bias trick; corr added after loop)
        #pragma unroll
        for (int q = 0; q < 8; ++q) {
            f2 a0, a1;
            a0[0] = fmaxf(acc0[2*q],   nb0); a0[1] = fmaxf(acc0[2*q+1], nb0);
            a1[0] = fmaxf(acc1[2*q],   nb1); a1[1] = fmaxf(acc1[2*q+1], nb1);
            s2[q] += a0 * g2v0 + a1 * g2v1;
        }
    }

    // exact bias correction: 8 bc per wave, both n-tiles fold into each element
    {
        const float corr = 8.0f * (b1v0 * g2v0 + b1v1 * g2v1);
        #pragma unroll
        for (int q = 0; q < 8; ++q) { s2[q][0] += corr; s2[q][1] += corr; }
    }

    __syncthreads();   // all waves done reading ldsA; reuse as ldsS

    {   // dump per-lane partials, stride 17 (conflict-free)
        float* base = ldsS + (wv*64 + lane)*17;
        #pragma unroll
        for (int q = 0; q < 8; ++q) { base[2*q] = s2[q][0]; base[2*q+1] = s2[q][1]; }
    }
    __syncthreads();

    // reduce over 8 waves x 32 lanes for each of 32 rows m
    // row m = (r&3) + 8*(r>>2) + 4*hf  ->  hf(m)=(m>>2)&1, r(m)=(m&3)|((m>>3)<<2)
    {
        const int m   = tid >> 4;        // 0..31
        const int ch  = tid & 15;        // 16 threads per row
        const int h_m = (m >> 2) & 1;
        const int r_m = (m & 3) | ((m >> 3) << 2);
        const int wvr = ch >> 1;         // 0..7
        const int ln0 = (ch & 1) * 16;
        float acc = 0.0f;
        #pragma unroll
        for (int q = 0; q < 16; ++q)
            acc += ldsS[(wvr*64 + h_m*32 + ln0 + q)*17 + r_m];
        red[m*16 + ch] = acc;
    }
    __syncthreads();

    if (tid < 32) {
        float tot = 0.0f;
        #pragma unroll
        for (int c2 = 0; c2 < 16; ++c2) tot += red[tid*16 + c2];
        atomicAdd(out + (size_t)b*NINT + i0 + tid,
                  tot * (1.0f/128.0f) + 0.5f * G2b[0]);
    }
}

// ---------------------------------------------------------------------------
extern "C" void kernel_launch(void* const* d_in, const int* in_sizes, int n_in,
                              void* d_out, int out_size, void* d_ws, size_t ws_size,
                              hipStream_t stream) {
    const float* binfo  = (const float*)d_in[0];
    const float* icoord = (const float*)d_in[1];
    const float* W0     = (const float*)d_in[2];
    const float* b0     = (const float*)d_in[3];
    const float* W1     = (const float*)d_in[4];
    const float* b1     = (const float*)d_in[5];
    const float* G0w    = (const float*)d_in[6];
    const float* G0b    = (const float*)d_in[7];
    const float* G1w    = (const float*)d_in[8];
    const float* G1b    = (const float*)d_in[9];
    const float* G2w    = (const float*)d_in[10];
    const float* G2b    = (const float*)d_in[11];

    float* aprime = (float*)d_ws;   // 4*128*64 fp32 = 128 KB scratch

    hipLaunchKernelGGL(bge_prep, dim3(BB*NBC/4), dim3(256), 0, stream,
                       binfo, W0, b0, W1, b1, G0w, G0b, aprime, (float*)d_out);
    hipLaunchKernelGGL(bge_main, dim3(NINT/32, BB, 2), dim3(512), 0, stream,
                       icoord, G0w, G1w, G1b, G2w, G2b, aprime,
                       (float*)d_out);
}

// Round 9
// 120.639 us; speedup vs baseline: 1.0401x; 1.0401x over previous
//
#include <hip/hip_runtime.h>
#include <hip/hip_bf16.h>

// Problem constants (B, NBC, H, W, HID, OUT = 4, 128, 64, 64, 64, 1)
// ALL tensors are float32 (reference uses jnp.float32 throughout).
#define BB   4
#define NBC  128
#define NINT 4096
#define HID  64

using short8  = __attribute__((ext_vector_type(8)))  short;  // 8 bf16 (4 VGPRs)
using float4v = __attribute__((ext_vector_type(4)))  float;  // 16x16 MFMA acc
using f2      = __attribute__((ext_vector_type(2)))  float;
using int4v   = __attribute__((ext_vector_type(4)))  int;

static __device__ __forceinline__ short f2bf(float f) {  // RNE, weights only
    __hip_bfloat16 h = __float2bfloat16(f);
    return __builtin_bit_cast(short, h);
}
static __device__ __forceinline__ unsigned fbits(float f) {
    return __builtin_bit_cast(unsigned, f);
}
// pack trunc-bf16(lo), trunc-bf16(hi) into one dword (verified R2-R8)
static __device__ __forceinline__ unsigned pack_bf_trunc(float lo, float hi) {
    return __builtin_amdgcn_perm(fbits(hi), fbits(lo), 0x07060302u);
}

// ---------------------------------------------------------------------------
// Kernel 1: boundary encoder + a' -> ws; ALSO zero-inits out (for atomics).
// ---------------------------------------------------------------------------
__global__ void __launch_bounds__(256) bge_prep(
    const float* __restrict__ binfo,  // (4,128,3)
    const float* __restrict__ W0,     // (3,64)
    const float* __restrict__ b0,     // (64)
    const float* __restrict__ W1,     // (64,64)
    const float* __restrict__ b1,     // (64)
    const float* __restrict__ G0w,    // (66,64)
    const float* __restrict__ G0b,    // (64)
    float* __restrict__ aprime,       // (4,128,64)
    float* __restrict__ out)          // (4,4096) -> zeroed here
{
    __shared__ float sW1[HID * HID];
    __shared__ float sG0[HID * HID];
    __shared__ float shv [4][HID];
    __shared__ float shv2[4][HID];

    const int tid = threadIdx.x;
    const int wv  = tid >> 6;
    const int t   = tid & 63;
    const int row = blockIdx.x * 4 + wv;

    // zero the output (harness poisons it 0xAA before every launch)
    const int g = blockIdx.x * 256 + tid;
    if (g < BB * NINT) out[g] = 0.0f;

    for (int idx = tid; idx < HID * HID / 4; idx += 256) {
        ((float4*)sW1)[idx] = ((const float4*)W1)[idx];
        ((float4*)sG0)[idx] = ((const float4*)G0w)[idx];
    }

    const float x0 = binfo[row*3+0];
    const float x1 = binfo[row*3+1];
    const float x2 = binfo[row*3+2];
    float h = fmaxf(x0*W0[t] + x1*W0[64+t] + x2*W0[128+t] + b0[t], 0.0f);
    shv[wv][t] = h;
    __syncthreads();

    float acc = b1[t];
    #pragma unroll 8
    for (int k = 0; k < HID; ++k) acc += shv[wv][k] * sW1[k*64 + t];
    shv2[wv][t] = fmaxf(acc, 0.0f);
    __syncthreads();

    float a = G0b[t];
    #pragma unroll 8
    for (int k = 0; k < HID; ++k) a += shv2[wv][k] * sG0[k*64 + t];
    aprime[row*HID + t] = a;
}

// ---------------------------------------------------------------------------
// Kernel 2 (R9): R7 kernel VERBATIM except __launch_bounds__(256, 2).
// Theory: default compiler reg-target (VGPR_Count 76-124 across R5-R8) is
// below the ~130-reg live set -> weight fragments rematerialized/reloaded
// every bc-iter (~390 VALU instr/iter measured vs ~130 in source). The
// (256,2) bound raises the budget to 256 VGPRs so fragments stay resident.
//   grid (128, 4, 2): i-tile of 32, batch, bc-half. 256 thr = 4 waves;
//   wave wv handles bc [zh*64 + wv*16, +16).
//   16x16x32 MFMA mappings [verified R7]: A[m=ln][k=q*8+jj], B[k][n=ln],
//   C/D col=ln, row=q*4+reg. Bias trick: relu(x+b)=max(x,-b)+b, corr once.
// ---------------------------------------------------------------------------
__global__ void __launch_bounds__(256, 2) bge_main(
    const float* __restrict__ icoord, // (4,4096,2)
    const float* __restrict__ G0w,    // (66,64)  rows 64,65 used here
    const float* __restrict__ G1w,    // (64,64)
    const float* __restrict__ G1b,    // (64)
    const float* __restrict__ G2w,    // (64,1)
    const float* __restrict__ G2b,    // (1)
    const float* __restrict__ aprime, // (4,128,64) fp32
    float* __restrict__ out)          // (4,4096), pre-zeroed
{
    __shared__ float sred[4][32];

    const int b    = blockIdx.y;
    const int i0   = blockIdx.x * 32;
    const int zh   = blockIdx.z;     // bc half (0/1)
    const int tid  = threadIdx.x;
    const int wv   = tid >> 6;       // 0..3
    const int lane = tid & 63;
    const int ln   = lane & 15;
    const int q    = lane >> 4;      // 0..3

    // coords for this lane's two i values (i-halves)
    const float2 cc0 = ((const float2*)icoord)[(size_t)b*NINT + i0 + ln];
    const float2 cc1 = ((const float2*)icoord)[(size_t)b*NINT + i0 + 16 + ln];

    // cre[ih][kh][pair]: c-contribution for k = kh*32 + q*8 + jj
    f2 cre[2][2][4];
    #pragma unroll
    for (int kh = 0; kh < 2; ++kh)
        #pragma unroll
        for (int jj = 0; jj < 8; ++jj) {
            const int k = kh*32 + q*8 + jj;
            const float gx = G0w[64*64 + k], gy = G0w[65*64 + k];
            cre[0][kh][jj>>1][jj&1] = cc0.x*gx + cc0.y*gy;
            cre[1][kh][jj>>1][jj&1] = cc1.x*gx + cc1.y*gy;
        }

    // B fragments of G1w: bfrag[kh][nt]
    short8 bfrag[2][4];
    #pragma unroll
    for (int kh = 0; kh < 2; ++kh)
        #pragma unroll
        for (int nt = 0; nt < 4; ++nt)
            #pragma unroll
            for (int jj = 0; jj < 8; ++jj)
                bfrag[kh][nt][jj] = f2bf(G1w[(kh*32 + q*8 + jj)*64 + nt*16 + ln]);

    // per-lane n-constants and exact bias correction
    float nb1[4], g2v[4];
    float corr = 0.0f;
    #pragma unroll
    for (int nt = 0; nt < 4; ++nt) {
        const float bv = G1b[nt*16 + ln];
        const float gv = G2w[nt*16 + ln];
        nb1[nt] = -bv;  g2v[nt] = gv;  corr += bv * gv;
    }

    f2 s[2][2];
    s[0][0] = (f2)0.0f; s[0][1] = (f2)0.0f; s[1][0] = (f2)0.0f; s[1][1] = (f2)0.0f;
    const float4v zc4 = (float4v)0.0f;

    const float* arow = aprime + ((size_t)b*NBC + zh*64 + wv*16)*HID;
    #pragma unroll 1
    for (int it = 0; it < 16; ++it, arow += HID) {
        // build A fragments (h1) for both i-halves and k-halves
        short8 af[2][2];
        #pragma unroll
        for (int kh = 0; kh < 2; ++kh) {
            const float4 v0 = *(const float4*)(arow + kh*32 + q*8);
            const float4 v1 = *(const float4*)(arow + kh*32 + q*8 + 4);
            f2 w[4];
            w[0][0]=v0.x; w[0][1]=v0.y; w[1][0]=v0.z; w[1][1]=v0.w;
            w[2][0]=v1.x; w[2][1]=v1.y; w[3][0]=v1.z; w[3][1]=v1.w;
            #pragma unroll
            for (int ih = 0; ih < 2; ++ih) {
                const f2 e0 = w[0] + cre[ih][kh][0];
                const f2 e1 = w[1] + cre[ih][kh][1];
                const f2 e2 = w[2] + cre[ih][kh][2];
                const f2 e3 = w[3] + cre[ih][kh][3];
                int4v di;
                di[0] = (int)pack_bf_trunc(fmaxf(e0[0],0.f), fmaxf(e0[1],0.f));
                di[1] = (int)pack_bf_trunc(fmaxf(e1[0],0.f), fmaxf(e1[1],0.f));
                di[2] = (int)pack_bf_trunc(fmaxf(e2[0],0.f), fmaxf(e2[1],0.f));
                di[3] = (int)pack_bf_trunc(fmaxf(e3[0],0.f), fmaxf(e3[1],0.f));
                af[ih][kh] = __builtin_bit_cast(short8, di);
            }
        }
        // 8 short chains: (i-half, n-tile), one 4-reg acc at a time
        #pragma unroll
        for (int ih = 0; ih < 2; ++ih)
            #pragma unroll
            for (int nt = 0; nt < 4; ++nt) {
                float4v acc = __builtin_amdgcn_mfma_f32_16x16x32_bf16(
                                  af[ih][0], bfrag[0][nt], zc4, 0, 0, 0);
                acc = __builtin_amdgcn_mfma_f32_16x16x32_bf16(
                                  af[ih][1], bfrag[1][nt], acc, 0, 0, 0);
                f2 m0, m1;
                m0[0] = fmaxf(acc[0], nb1[nt]); m0[1] = fmaxf(acc[1], nb1[nt]);
                m1[0] = fmaxf(acc[2], nb1[nt]); m1[1] = fmaxf(acc[3], nb1[nt]);
                s[ih][0] += m0 * g2v[nt];
                s[ih][1] += m1 * g2v[nt];
            }
    }

    // exact bias correction: each s element covered 16 bc x 4 n-tiles
    {
        const f2 cadd = (f2)(16.0f * corr);
        s[0][0] += cadd; s[0][1] += cadd; s[1][0] += cadd; s[1][1] += cadd;
    }

    // reduce over n within each 16-lane group (butterfly), then LDS + atomic
    float v8[8] = { s[0][0][0], s[0][0][1], s[0][1][0], s[0][1][1],
                    s[1][0][0], s[1][0][1], s[1][1][0], s[1][1][1] };
    #pragma unroll
    for (int t = 0; t < 8; ++t) {
        float v = v8[t];
        v += __shfl_xor(v, 1);
        v += __shfl_xor(v, 2);
        v += __shfl_xor(v, 4);
        v += __shfl_xor(v, 8);
        v8[t] = v;
    }
    if (ln == 0) {
        #pragma unroll
        for (int ih = 0; ih < 2; ++ih)
            #pragma unroll
            for (int r = 0; r < 4; ++r)
                sred[wv][ih*16 + q*4 + r] = v8[ih*4 + r];
    }
    __syncthreads();

    if (tid < 32) {
        const float tot = sred[0][tid] + sred[1][tid] + sred[2][tid] + sred[3][tid];
        atomicAdd(out + (size_t)b*NINT + i0 + tid,
                  tot * (1.0f/128.0f) + 0.5f * G2b[0]);
    }
}

// ---------------------------------------------------------------------------
extern "C" void kernel_launch(void* const* d_in, const int* in_sizes, int n_in,
                              void* d_out, int out_size, void* d_ws, size_t ws_size,
                              hipStream_t stream) {
    const float* binfo  = (const float*)d_in[0];
    const float* icoord = (const float*)d_in[1];
    const float* W0     = (const float*)d_in[2];
    const float* b0     = (const float*)d_in[3];
    const float* W1     = (const float*)d_in[4];
    const float* b1     = (const float*)d_in[5];
    const float* G0w    = (const float*)d_in[6];
    const float* G0b    = (const float*)d_in[7];
    const float* G1w    = (const float*)d_in[8];
    const float* G1b    = (const float*)d_in[9];
    const float* G2w    = (const float*)d_in[10];
    const float* G2b    = (const float*)d_in[11];

    float* aprime = (float*)d_ws;   // 4*128*64 fp32 = 128 KB scratch

    hipLaunchKernelGGL(bge_prep, dim3(BB*NBC/4), dim3(256), 0, stream,
                       binfo, W0, b0, W1, b1, G0w, G0b, aprime, (float*)d_out);
    hipLaunchKernelGGL(bge_main, dim3(NINT/32, BB, 2), dim3(256), 0, stream,
                       icoord, G0w, G1w, G1b, G2w, G2b, aprime,
                       (float*)d_out);
}

// Round 10
// 116.150 us; speedup vs baseline: 1.0803x; 1.0387x over previous
//
#include <hip/hip_runtime.h>
#include <hip/hip_bf16.h>

// Problem constants (B, NBC, H, W, HID, OUT = 4, 128, 64, 64, 64, 1)
// ALL tensors are float32 (reference uses jnp.float32 throughout).
#define BB   4
#define NBC  128
#define NINT 4096
#define HID  64

using short8  = __attribute__((ext_vector_type(8)))  short;  // 8 bf16 (4 VGPRs)
using float4v = __attribute__((ext_vector_type(4)))  float;  // 16x16 MFMA acc
using f2      = __attribute__((ext_vector_type(2)))  float;
using int4v   = __attribute__((ext_vector_type(4)))  int;

static __device__ __forceinline__ short f2bf(float f) {  // RNE, weights only
    __hip_bfloat16 h = __float2bfloat16(f);
    return __builtin_bit_cast(short, h);
}
static __device__ __forceinline__ unsigned fbits(float f) {
    return __builtin_bit_cast(unsigned, f);
}
// pack trunc-bf16(lo), trunc-bf16(hi) into one dword (verified R2-R9)
static __device__ __forceinline__ unsigned pack_bf_trunc(float lo, float hi) {
    return __builtin_amdgcn_perm(fbits(hi), fbits(lo), 0x07060302u);
}

// ---------------------------------------------------------------------------
// Kernel 1: boundary encoder + a' -> ws; ALSO zero-inits out (for atomics).
// ---------------------------------------------------------------------------
__global__ void __launch_bounds__(256) bge_prep(
    const float* __restrict__ binfo,  // (4,128,3)
    const float* __restrict__ W0,     // (3,64)
    const float* __restrict__ b0,     // (64)
    const float* __restrict__ W1,     // (64,64)
    const float* __restrict__ b1,     // (64)
    const float* __restrict__ G0w,    // (66,64)
    const float* __restrict__ G0b,    // (64)
    float* __restrict__ aprime,       // (4,128,64)
    float* __restrict__ out)          // (4,4096) -> zeroed here
{
    __shared__ float sW1[HID * HID];
    __shared__ float sG0[HID * HID];
    __shared__ float shv [4][HID];
    __shared__ float shv2[4][HID];

    const int tid = threadIdx.x;
    const int wv  = tid >> 6;
    const int t   = tid & 63;
    const int row = blockIdx.x * 4 + wv;

    // zero the output (harness poisons it 0xAA before every launch)
    const int g = blockIdx.x * 256 + tid;
    if (g < BB * NINT) out[g] = 0.0f;

    for (int idx = tid; idx < HID * HID / 4; idx += 256) {
        ((float4*)sW1)[idx] = ((const float4*)W1)[idx];
        ((float4*)sG0)[idx] = ((const float4*)G0w)[idx];
    }

    const float x0 = binfo[row*3+0];
    const float x1 = binfo[row*3+1];
    const float x2 = binfo[row*3+2];
    float h = fmaxf(x0*W0[t] + x1*W0[64+t] + x2*W0[128+t] + b0[t], 0.0f);
    shv[wv][t] = h;
    __syncthreads();

    float acc = b1[t];
    #pragma unroll 8
    for (int k = 0; k < HID; ++k) acc += shv[wv][k] * sW1[k*64 + t];
    shv2[wv][t] = fmaxf(acc, 0.0f);
    __syncthreads();

    float a = G0b[t];
    #pragma unroll 8
    for (int k = 0; k < HID; ++k) a += shv2[wv][k] * sG0[k*64 + t];
    aprime[row*HID + t] = a;
}

// ---------------------------------------------------------------------------
// Kernel 2 (R10): R9 math + latency attack.
//   grid (128, 4, 4): i-tile of 32, batch, bc-quarter -> 2048 blocks
//   (32 waves/CU launched; ~24 resident at VGPR~100). 256 thr = 4 waves;
//   wave wv handles bc [zq*32 + wv*8, +8) -> 8 iters.
//   Register double-buffer prefetch: iter t+1's a'-row float4s issued before
//   iter t's MFMA section (loads in flight across compute).
//   16x16x32 MFMA mappings [verified R7/R9]: A[m=ln][k=q*8+jj], B[k][n=ln],
//   C/D col=ln, row=q*4+reg. Bias trick: relu(x+b)=max(x,-b)+b, corr once.
//   Quarters merged via atomicAdd (out zeroed in prep; R7-verified).
// ---------------------------------------------------------------------------
__global__ void __launch_bounds__(256) bge_main(
    const float* __restrict__ icoord, // (4,4096,2)
    const float* __restrict__ G0w,    // (66,64)  rows 64,65 used here
    const float* __restrict__ G1w,    // (64,64)
    const float* __restrict__ G1b,    // (64)
    const float* __restrict__ G2w,    // (64,1)
    const float* __restrict__ G2b,    // (1)
    const float* __restrict__ aprime, // (4,128,64) fp32
    float* __restrict__ out)          // (4,4096), pre-zeroed
{
    __shared__ float sred[4][32];

    const int b    = blockIdx.y;
    const int i0   = blockIdx.x * 32;
    const int zq   = blockIdx.z;     // bc quarter (0..3)
    const int tid  = threadIdx.x;
    const int wv   = tid >> 6;       // 0..3
    const int lane = tid & 63;
    const int ln   = lane & 15;
    const int q    = lane >> 4;      // 0..3

    // coords for this lane's two i values (i-halves)
    const float2 cc0 = ((const float2*)icoord)[(size_t)b*NINT + i0 + ln];
    const float2 cc1 = ((const float2*)icoord)[(size_t)b*NINT + i0 + 16 + ln];

    // cre[ih][kh][pair]: c-contribution for k = kh*32 + q*8 + jj
    f2 cre[2][2][4];
    #pragma unroll
    for (int kh = 0; kh < 2; ++kh)
        #pragma unroll
        for (int jj = 0; jj < 8; ++jj) {
            const int k = kh*32 + q*8 + jj;
            const float gx = G0w[64*64 + k], gy = G0w[65*64 + k];
            cre[0][kh][jj>>1][jj&1] = cc0.x*gx + cc0.y*gy;
            cre[1][kh][jj>>1][jj&1] = cc1.x*gx + cc1.y*gy;
        }

    // B fragments of G1w: bfrag[kh][nt]
    short8 bfrag[2][4];
    #pragma unroll
    for (int kh = 0; kh < 2; ++kh)
        #pragma unroll
        for (int nt = 0; nt < 4; ++nt)
            #pragma unroll
            for (int jj = 0; jj < 8; ++jj)
                bfrag[kh][nt][jj] = f2bf(G1w[(kh*32 + q*8 + jj)*64 + nt*16 + ln]);

    // per-lane n-constants and exact bias correction
    float nb1[4], g2v[4];
    float corr = 0.0f;
    #pragma unroll
    for (int nt = 0; nt < 4; ++nt) {
        const float bv = G1b[nt*16 + ln];
        const float gv = G2w[nt*16 + ln];
        nb1[nt] = -bv;  g2v[nt] = gv;  corr += bv * gv;
    }

    f2 s[2][2];
    s[0][0] = (f2)0.0f; s[0][1] = (f2)0.0f; s[1][0] = (f2)0.0f; s[1][1] = (f2)0.0f;
    const float4v zc4 = (float4v)0.0f;

    const float* ar = aprime + ((size_t)b*NBC + zq*32 + wv*8)*HID;

    // prime the register double-buffer with iter 0's row
    float4 cv00 = *(const float4*)(ar + q*8);
    float4 cv01 = *(const float4*)(ar + q*8 + 4);
    float4 cv10 = *(const float4*)(ar + 32 + q*8);
    float4 cv11 = *(const float4*)(ar + 32 + q*8 + 4);

    #pragma unroll 1
    for (int it = 0; it < 8; ++it, ar += HID) {
        // prefetch next iter's row (last iter: re-load current, discarded)
        const float* nr = ar + ((it < 7) ? HID : 0);
        const float4 nv00 = *(const float4*)(nr + q*8);
        const float4 nv01 = *(const float4*)(nr + q*8 + 4);
        const float4 nv10 = *(const float4*)(nr + 32 + q*8);
        const float4 nv11 = *(const float4*)(nr + 32 + q*8 + 4);

        // build A fragments (h1) from the current buffer
        short8 af[2][2];
        #pragma unroll
        for (int kh = 0; kh < 2; ++kh) {
            const float4 v0 = kh ? cv10 : cv00;
            const float4 v1 = kh ? cv11 : cv01;
            f2 w[4];
            w[0][0]=v0.x; w[0][1]=v0.y; w[1][0]=v0.z; w[1][1]=v0.w;
            w[2][0]=v1.x; w[2][1]=v1.y; w[3][0]=v1.z; w[3][1]=v1.w;
            #pragma unroll
            for (int ih = 0; ih < 2; ++ih) {
                const f2 e0 = __builtin_elementwise_max(w[0] + cre[ih][kh][0], (f2)0.0f);
                const f2 e1 = __builtin_elementwise_max(w[1] + cre[ih][kh][1], (f2)0.0f);
                const f2 e2 = __builtin_elementwise_max(w[2] + cre[ih][kh][2], (f2)0.0f);
                const f2 e3 = __builtin_elementwise_max(w[3] + cre[ih][kh][3], (f2)0.0f);
                int4v di;
                di[0] = (int)pack_bf_trunc(e0[0], e0[1]);
                di[1] = (int)pack_bf_trunc(e1[0], e1[1]);
                di[2] = (int)pack_bf_trunc(e2[0], e2[1]);
                di[3] = (int)pack_bf_trunc(e3[0], e3[1]);
                af[ih][kh] = __builtin_bit_cast(short8, di);
            }
        }

        // 8 short chains: (i-half, n-tile), one 4-reg acc at a time
        #pragma unroll
        for (int ih = 0; ih < 2; ++ih)
            #pragma unroll
            for (int nt = 0; nt < 4; ++nt) {
                float4v acc = __builtin_amdgcn_mfma_f32_16x16x32_bf16(
                                  af[ih][0], bfrag[0][nt], zc4, 0, 0, 0);
                acc = __builtin_amdgcn_mfma_f32_16x16x32_bf16(
                                  af[ih][1], bfrag[1][nt], acc, 0, 0, 0);
                f2 a01; a01[0] = acc[0]; a01[1] = acc[1];
                f2 a23; a23[0] = acc[2]; a23[1] = acc[3];
                a01 = __builtin_elementwise_max(a01, (f2)nb1[nt]);
                a23 = __builtin_elementwise_max(a23, (f2)nb1[nt]);
                s[ih][0] += a01 * g2v[nt];
                s[ih][1] += a23 * g2v[nt];
            }

        // rotate the double-buffer
        cv00 = nv00; cv01 = nv01; cv10 = nv10; cv11 = nv11;
    }

    // exact bias correction: each s element covered 8 bc x 4 n-tiles
    {
        const f2 cadd = (f2)(8.0f * corr);
        s[0][0] += cadd; s[0][1] += cadd; s[1][0] += cadd; s[1][1] += cadd;
    }

    // reduce over n within each 16-lane group (butterfly), then LDS + atomic
    float v8[8] = { s[0][0][0], s[0][0][1], s[0][1][0], s[0][1][1],
                    s[1][0][0], s[1][0][1], s[1][1][0], s[1][1][1] };
    #pragma unroll
    for (int t = 0; t < 8; ++t) {
        float v = v8[t];
        v += __shfl_xor(v, 1);
        v += __shfl_xor(v, 2);
        v += __shfl_xor(v, 4);
        v += __shfl_xor(v, 8);
        v8[t] = v;
    }
    if (ln == 0) {
        #pragma unroll
        for (int ih = 0; ih < 2; ++ih)
            #pragma unroll
            for (int r = 0; r < 4; ++r)
                sred[wv][ih*16 + q*4 + r] = v8[ih*4 + r];
    }
    __syncthreads();

    if (tid < 32) {
        const float tot = sred[0][tid] + sred[1][tid] + sred[2][tid] + sred[3][tid];
        atomicAdd(out + (size_t)b*NINT + i0 + tid,
                  tot * (1.0f/128.0f) + 0.25f * G2b[0]);
    }
}

// ---------------------------------------------------------------------------
extern "C" void kernel_launch(void* const* d_in, const int* in_sizes, int n_in,
                              void* d_out, int out_size, void* d_ws, size_t ws_size,
                              hipStream_t stream) {
    const float* binfo  = (const float*)d_in[0];
    const float* icoord = (const float*)d_in[1];
    const float* W0     = (const float*)d_in[2];
    const float* b0     = (const float*)d_in[3];
    const float* W1     = (const float*)d_in[4];
    const float* b1     = (const float*)d_in[5];
    const float* G0w    = (const float*)d_in[6];
    const float* G0b    = (const float*)d_in[7];
    const float* G1w    = (const float*)d_in[8];
    const float* G1b    = (const float*)d_in[9];
    const float* G2w    = (const float*)d_in[10];
    const float* G2b    = (const float*)d_in[11];

    float* aprime = (float*)d_ws;   // 4*128*64 fp32 = 128 KB scratch

    hipLaunchKernelGGL(bge_prep, dim3(BB*NBC/4), dim3(256), 0, stream,
                       binfo, W0, b0, W1, b1, G0w, G0b, aprime, (float*)d_out);
    hipLaunchKernelGGL(bge_main, dim3(NINT/32, BB, 4), dim3(256), 0, stream,
                       icoord, G0w, G1w, G1b, G2w, G2b, aprime,
                       (float*)d_out);
}